// Round 9
// baseline (305.440 us; speedup 1.0000x reference)
//
#include <hip/hip_runtime.h>

typedef unsigned short u16;
typedef __bf16 bf16x8 __attribute__((ext_vector_type(8)));
typedef float f32x4 __attribute__((ext_vector_type(4)));

#define NHEAD 12
#define LQ 1024
#define HDIM 64
#define DIMM 768

__device__ __forceinline__ u16 f2b(float f) {
  unsigned u = __float_as_uint(f);
  u += 0x7fffu + ((u >> 16) & 1u);   // RNE; inputs are finite
  return (u16)(u >> 16);
}
__device__ __forceinline__ float b2f(u16 v) {
  return __uint_as_float(((unsigned)v) << 16);
}
__device__ __forceinline__ unsigned cvt_pk(float lo, float hi) {
  unsigned r;
  asm("v_cvt_pk_bf16_f32 %0, %1, %2" : "=v"(r) : "v"(lo), "v"(hi));
  return r;
}
__device__ __forceinline__ void async16(const void* g, void* l) {
  __builtin_amdgcn_global_load_lds(
      (const __attribute__((address_space(1))) void*)g,
      (__attribute__((address_space(3))) void*)l, 16, 0, 0);
}
__device__ __forceinline__ uint2 shfl_u2(uint2 v, int src) {
  uint2 r;
  r.x = (unsigned)__shfl((int)v.x, src, 64);
  r.y = (unsigned)__shfl((int)v.y, src, 64);
  return r;
}

// ---------------- f32 -> bf16 convert ----------------
__global__ __launch_bounds__(256) void cvt_kernel(const float* __restrict__ in,
                                                  u16* __restrict__ out, int n4) {
  int i = blockIdx.x * 256 + threadIdx.x;
  if (i >= n4) return;
  const float4 v = reinterpret_cast<const float4*>(in)[i];
  ushort4 o;
  o.x = f2b(v.x); o.y = f2b(v.y); o.z = f2b(v.z); o.w = f2b(v.w);
  reinterpret_cast<ushort4*>(out)[i] = o;
}

// rel tables -> padded bf16 [64][64] (row 63 zero, never indexed)
__global__ __launch_bounds__(256) void cvt_rel(const float* __restrict__ rph,
                                               const float* __restrict__ rpw,
                                               u16* __restrict__ rphb,
                                               u16* __restrict__ rpwb) {
  int i = blockIdx.x * 256 + threadIdx.x;   // 0..8191
  int tab = i >> 12, idx = i & 4095;
  int m = idx >> 6, d = idx & 63;
  const float* src = tab ? rpw : rph;
  u16* dst = tab ? rpwb : rphb;
  dst[idx] = (m < 63) ? f2b(src[m * HDIM + d]) : (u16)0;
}

// ---------------- QKV GEMM: C = A(8192x768) * Bt(2304x768)^T + bias ----------------
// BK=64, dbuf, XCD swizzle, ^(row&7) involution staging (r8, passing state)
__global__ __launch_bounds__(256) void gemm_qkv(const u16* __restrict__ A,
                                                const u16* __restrict__ Bt,
                                                const float* __restrict__ bias,
                                                u16* __restrict__ qb,
                                                u16* __restrict__ kb,
                                                u16* __restrict__ vtb) {
  __shared__ u16 la[2][128 * 64];
  __shared__ u16 lb[2][128 * 64];
  const int K = DIMM;
  int t = threadIdx.x;
  int lane = t & 63, wv = t >> 6;
  int l15 = lane & 15, l4 = lane >> 4;
  int swz = (blockIdx.x & 7) * 144 + (blockIdx.x >> 3);   // 1152 = 8*144
  int bm = swz / 18, bn = swz % 18;
  int m0 = bm * 128, n0 = bn * 128;
  int wm = (wv >> 1) * 64, wn = (wv & 1) * 64;

  auto stage = [&](int s, int buf) {
    int k0 = s * 64;
    #pragma unroll
    for (int i = 0; i < 4; ++i) {
      int c = i * 256 + t;
      int row = c >> 3, co = c & 7;
      int g = co ^ (row & 7);          // source pre-swizzle; LDS stays linear
      async16(A + (m0 + row) * K + k0 + g * 8, (char*)&la[buf][0] + c * 16);
      async16(Bt + (n0 + row) * K + k0 + g * 8, (char*)&lb[buf][0] + c * 16);
    }
  };

  f32x4 acc[4][4];
  #pragma unroll
  for (int i = 0; i < 4; ++i)
    #pragma unroll
    for (int j = 0; j < 4; ++j) acc[i][j] = {0.f, 0.f, 0.f, 0.f};

  stage(0, 0);
  #pragma unroll 2
  for (int s = 0; s < 12; ++s) {
    int cur = s & 1;
    __syncthreads();                      // drains own vmcnt(0): buf[cur] landed
    if (s + 1 < 12) stage(s + 1, cur ^ 1);
    bf16x8 af[4][2], bfr[4][2];
    #pragma unroll
    for (int mi = 0; mi < 4; ++mi) {
      int row = wm + mi * 16 + l15;
      #pragma unroll
      for (int ks2 = 0; ks2 < 2; ++ks2)
        af[mi][ks2] = *reinterpret_cast<const bf16x8*>(
            &la[cur][row * 64 + (((ks2 << 2) + l4) ^ (row & 7)) * 8]);
    }
    #pragma unroll
    for (int nj = 0; nj < 4; ++nj) {
      int row = wn + nj * 16 + l15;
      #pragma unroll
      for (int ks2 = 0; ks2 < 2; ++ks2)
        bfr[nj][ks2] = *reinterpret_cast<const bf16x8*>(
            &lb[cur][row * 64 + (((ks2 << 2) + l4) ^ (row & 7)) * 8]);
    }
    #pragma unroll
    for (int mi = 0; mi < 4; ++mi)
      #pragma unroll
      for (int nj = 0; nj < 4; ++nj)
        #pragma unroll
        for (int ks2 = 0; ks2 < 2; ++ks2)
          acc[mi][nj] = __builtin_amdgcn_mfma_f32_16x16x32_bf16(
              af[mi][ks2], bfr[nj][ks2], acc[mi][nj], 0, 0, 0);
  }

  int part = (n0 >> 7) / 6;  // 0:q 1:k 2:v (768 = 6 tiles of 128)
  #pragma unroll
  for (int nj = 0; nj < 4; ++nj) {
    int n = n0 + wn + nj * 16 + l15;
    float bv = bias[n];
    int d = n & 63;
    int head = (n >> 6) % NHEAD;
    #pragma unroll
    for (int mi = 0; mi < 4; ++mi) {
      #pragma unroll
      for (int r = 0; r < 4; ++r) {
        int m = m0 + wm + mi * 16 + l4 * 4 + r;
        int b = m >> 10, li = m & 1023;
        int bh = b * NHEAD + head;
        u16 o = f2b(acc[mi][nj][r] + bv);
        if (part == 0)      qb[(bh * LQ + li) * HDIM + d] = o;
        else if (part == 1) kb[(bh * LQ + li) * HDIM + d] = o;
        else                vtb[(bh * HDIM + d) * LQ + li] = o;
      }
    }
  }
}

// ---------------- flash attention, BARRIER-FREE ----------------
// 4 independent waves, QBLK=64 (wave -> 16 rows), KV chunks of 64.
// K/V are read DIRECTLY from global (L2/L1-resident: per XCD 12 bh x 256KB = 3MB
// L2-fit via swizzle; per-chunk 8KB shared by 4 waves via L1) — no LDS staging,
// no __syncthreads anywhere (lds_th/tw are wave-private). Latency hidden by TLP.
// SWAPPED operands: mfma(K,Q) / mfma(V,P); P redistributed in-register; Tw in regs
__global__ __launch_bounds__(256) void attn_kernel(const u16* __restrict__ qb,
                                                   const u16* __restrict__ kb,
                                                   const u16* __restrict__ vtb,
                                                   const u16* __restrict__ rphb,
                                                   const u16* __restrict__ rpwb,
                                                   u16* __restrict__ ao) {
  __shared__ u16 lds_th[64 * 72];      // T-tables, bf16, padded stride 72
  __shared__ u16 lds_tw[64 * 72];      // 18.4 KB total

  int swz = (blockIdx.x & 7) * 192 + (blockIdx.x >> 3);   // 1536 = 8*192
  int bh = swz >> 4;
  int q0 = (swz & 15) * 64;
  int t = threadIdx.x;
  int wv = t >> 6, lane = t & 63;
  int l15 = lane & 15, l4 = lane >> 4;

  // Q fragments (2 x K=32) straight from global
  bf16x8 qf[2];
  {
    const u16* qsrc = qb + (bh * LQ + q0 + wv * 16 + l15) * HDIM + l4 * 8;
    qf[0] = *reinterpret_cast<const bf16x8*>(qsrc);
    qf[1] = *reinterpret_cast<const bf16x8*>(qsrc + 32);
  }

  // T-tables via MFMA: wave wv owns rows [wv*16, wv*16+16) (wave-private)
  #pragma unroll
  for (int c = 0; c < 4; ++c) {
    f32x4 th = {0.f, 0.f, 0.f, 0.f}, tw = {0.f, 0.f, 0.f, 0.f};
    #pragma unroll
    for (int ks2 = 0; ks2 < 2; ++ks2) {
      bf16x8 bhf = *reinterpret_cast<const bf16x8*>(&rphb[(c * 16 + l15) * HDIM + ks2 * 32 + l4 * 8]);
      bf16x8 bwf = *reinterpret_cast<const bf16x8*>(&rpwb[(c * 16 + l15) * HDIM + ks2 * 32 + l4 * 8]);
      th = __builtin_amdgcn_mfma_f32_16x16x32_bf16(qf[ks2], bhf, th, 0, 0, 0);
      tw = __builtin_amdgcn_mfma_f32_16x16x32_bf16(qf[ks2], bwf, tw, 0, 0, 0);
    }
    #pragma unroll
    for (int r = 0; r < 4; ++r) {
      int row = wv * 16 + l4 * 4 + r;
      lds_th[row * 72 + c * 16 + l15] = f2b(th[r]);
      lds_tw[row * 72 + c * 16 + l15] = f2b(tw[r]);
    }
  }

  // per-lane row constants (lane owns q-row l15 of its wave's 16 rows)
  int gq = q0 + wv * 16 + l15;
  int hq = gq >> 5, wq = gq & 31;
  int lrow = wv * 16 + l15;
  const u16* thp = &lds_th[lrow * 72 + hq + 31];   // [-k1]
  const u16* twp = &lds_tw[lrow * 72 + wq + 31];   // [-k2]

  // Tw hoist: only 8 distinct Tw values per lane, chunk-invariant. Load once
  // (own wave's rows; DS in-order per wave, no barrier needed).
  float tw_reg[8];
  #pragma unroll
  for (int j = 0; j < 8; ++j) {
    int k2 = (j >> 2) * 16 + l4 * 4 + (j & 3);
    tw_reg[j] = b2f(twp[-k2]);
  }

  float m_run = -1e30f, l_run = 0.f;
  f32x4 acc_o[4];
  #pragma unroll
  for (int dj = 0; dj < 4; ++dj) acc_o[dj] = {0.f, 0.f, 0.f, 0.f};

  // bpermute sources for P redistribution (fixed per lane)
  int srcA = l15 + (l4 & 1) * 32;
  int srcB = srcA + 16;
  bool hiG = (l4 >> 1) & 1;

  const u16* kbase = kb + bh * LQ * HDIM;          // [key][64]
  const u16* vbase = vtb + bh * HDIM * LQ;         // [d][1024]

  for (int cidx = 0; cidx < 16; ++cidx) {
    int kv0 = cidx * 64;

    // QK^T swapped, K fragments DIRECT from global:
    // lane reads K[kv0 + nj*16 + l15][(ks2*4+l4)*8 ..+8) — 16B aligned
    f32x4 sc[4];
    __builtin_amdgcn_s_setprio(1);
    #pragma unroll
    for (int nj = 0; nj < 4; ++nj) {
      f32x4 a = {0.f, 0.f, 0.f, 0.f};
      #pragma unroll
      for (int ks2 = 0; ks2 < 2; ++ks2) {
        bf16x8 kf = *reinterpret_cast<const bf16x8*>(
            kbase + (kv0 + nj * 16 + l15) * HDIM + (ks2 * 4 + l4) * 8);
        a = __builtin_amdgcn_mfma_f32_16x16x32_bf16(kf, qf[ks2], a, 0, 0, 0);
      }
      sc[nj] = a;
    }
    __builtin_amdgcn_s_setprio(0);

    // scores + bias (all 16 belong to q-row l15)
    int kv5 = kv0 >> 5;
    float th0 = b2f(thp[-kv5]);        // k1 = kv5   (nj 0,1)
    float th1 = b2f(thp[-kv5 - 1]);    // k1 = kv5+1 (nj 2,3)
    float p[4][4];
    float cmax = -1e30f;
    #pragma unroll
    for (int nj = 0; nj < 4; ++nj) {
      float thv = (nj < 2) ? th0 : th1;
      #pragma unroll
      for (int r = 0; r < 4; ++r) {
        float s = fmaf(sc[nj][r], 0.125f, thv) + tw_reg[(nj & 1) * 4 + r];
        p[nj][r] = s;
        cmax = fmaxf(cmax, s);
      }
    }
    cmax = fmaxf(cmax, __shfl_xor(cmax, 16));
    cmax = fmaxf(cmax, __shfl_xor(cmax, 32));

    // defer-max (T13): rescale only when some row grew by > 8
    if (!__all(cmax <= m_run + 8.0f)) {
      float mn = fmaxf(m_run, cmax);
      float scl = __expf(m_run - mn);
      m_run = mn;
      l_run *= scl;
      #pragma unroll
      for (int dj = 0; dj < 4; ++dj)
        #pragma unroll
        for (int r = 0; r < 4; ++r) acc_o[dj][r] *= scl;
    }

    float psum = 0.f;
    #pragma unroll
    for (int nj = 0; nj < 4; ++nj)
      #pragma unroll
      for (int r = 0; r < 4; ++r) {
        p[nj][r] = __expf(p[nj][r] - m_run);
        psum += p[nj][r];
      }
    psum += __shfl_xor(psum, 16);
    psum += __shfl_xor(psum, 32);
    l_run += psum;

    // P -> bf16 packed, redistribute to B-fragment layout in-register (T12):
    // pf[ks2][i] = P[l15][ks2*32 + l4*8 + i]
    uint2 w4[4];
    #pragma unroll
    for (int nj = 0; nj < 4; ++nj) {
      w4[nj].x = cvt_pk(p[nj][0], p[nj][1]);
      w4[nj].y = cvt_pk(p[nj][2], p[nj][3]);
    }
    bf16x8 pf[2];
    #pragma unroll
    for (int ks2 = 0; ks2 < 2; ++ks2) {
      uint2 lo0 = shfl_u2(w4[ks2 * 2 + 0], srcA);
      uint2 lo1 = shfl_u2(w4[ks2 * 2 + 1], srcA);
      uint2 hi0 = shfl_u2(w4[ks2 * 2 + 0], srcB);
      uint2 hi1 = shfl_u2(w4[ks2 * 2 + 1], srcB);
      union { uint4 u; bf16x8 b; } cv;
      cv.u.x = hiG ? lo1.x : lo0.x;
      cv.u.y = hiG ? lo1.y : lo0.y;
      cv.u.z = hiG ? hi1.x : hi0.x;
      cv.u.w = hiG ? hi1.y : hi0.y;
      pf[ks2] = cv.b;
    }

    // PV swapped, V^T fragments DIRECT from global:
    // lane reads Vt[dj*16 + l15][kv0 + (ks2*4+l4)*8 ..+8)
    __builtin_amdgcn_s_setprio(1);
    #pragma unroll
    for (int dj = 0; dj < 4; ++dj) {
      #pragma unroll
      for (int ks2 = 0; ks2 < 2; ++ks2) {
        bf16x8 vf = *reinterpret_cast<const bf16x8*>(
            vbase + (dj * 16 + l15) * LQ + kv0 + (ks2 * 4 + l4) * 8);
        acc_o[dj] = __builtin_amdgcn_mfma_f32_16x16x32_bf16(vf, pf[ks2], acc_o[dj], 0, 0, 0);
      }
    }
    __builtin_amdgcn_s_setprio(0);
  }

  // epilogue: normalize, packed 8B stores; lane owns q-row gq, d = dj*16 + l4*4 + r
  int b = bh / NHEAD, head = bh % NHEAD;
  float inv = 1.f / l_run;
  u16* orow = ao + (b * LQ + gq) * DIMM + head * HDIM;
  #pragma unroll
  for (int dj = 0; dj < 4; ++dj) {
    uint2 pk;
    pk.x = cvt_pk(acc_o[dj][0] * inv, acc_o[dj][1] * inv);
    pk.y = cvt_pk(acc_o[dj][2] * inv, acc_o[dj][3] * inv);
    *reinterpret_cast<uint2*>(&orow[dj * 16 + l4 * 4]) = pk;
  }
}

// ---------------- proj GEMM: out = A(8192x768) * Bt(768x768)^T + bias (f32 out) ----------------
__global__ __launch_bounds__(256) void gemm_proj(const u16* __restrict__ A,
                                                 const u16* __restrict__ Bt,
                                                 const float* __restrict__ bias,
                                                 float* __restrict__ out) {
  __shared__ u16 la[2][128 * 64];
  __shared__ u16 lb[2][128 * 64];
  const int K = DIMM;
  int t = threadIdx.x;
  int lane = t & 63, wv = t >> 6;
  int l15 = lane & 15, l4 = lane >> 4;
  int swz = (blockIdx.x & 7) * 48 + (blockIdx.x >> 3);    // 384 = 8*48
  int bm = swz / 6, bn = swz % 6;
  int m0 = bm * 128, n0 = bn * 128;
  int wm = (wv >> 1) * 64, wn = (wv & 1) * 64;

  auto stage = [&](int s, int buf) {
    int k0 = s * 64;
    #pragma unroll
    for (int i = 0; i < 4; ++i) {
      int c = i * 256 + t;
      int row = c >> 3, co = c & 7;
      int g = co ^ (row & 7);
      async16(A + (m0 + row) * K + k0 + g * 8, (char*)&la[buf][0] + c * 16);
      async16(Bt + (n0 + row) * K + k0 + g * 8, (char*)&lb[buf][0] + c * 16);
    }
  };

  f32x4 acc[4][4];
  #pragma unroll
  for (int i = 0; i < 4; ++i)
    #pragma unroll
    for (int j = 0; j < 4; ++j) acc[i][j] = {0.f, 0.f, 0.f, 0.f};

  stage(0, 0);
  #pragma unroll 2
  for (int s = 0; s < 12; ++s) {
    int cur = s & 1;
    __syncthreads();
    if (s + 1 < 12) stage(s + 1, cur ^ 1);
    bf16x8 af[4][2], bfr[4][2];
    #pragma unroll
    for (int mi = 0; mi < 4; ++mi) {
      int row = wm + mi * 16 + l15;
      #pragma unroll
      for (int ks2 = 0; ks2 < 2; ++ks2)
        af[mi][ks2] = *reinterpret_cast<const bf16x8*>(
            &la[cur][row * 64 + (((ks2 << 2) + l4) ^ (row & 7)) * 8]);
    }
    #pragma unroll
    for (int nj = 0; nj < 4; ++nj) {
      int row = wn + nj * 16 + l15;
      #pragma unroll
      for (int ks2 = 0; ks2 < 2; ++ks2)
        bfr[nj][ks2] = *reinterpret_cast<const bf16x8*>(
            &lb[cur][row * 64 + (((ks2 << 2) + l4) ^ (row & 7)) * 8]);
    }
    #pragma unroll
    for (int mi = 0; mi < 4; ++mi)
      #pragma unroll
      for (int nj = 0; nj < 4; ++nj)
        #pragma unroll
        for (int ks2 = 0; ks2 < 2; ++ks2)
          acc[mi][nj] = __builtin_amdgcn_mfma_f32_16x16x32_bf16(
              af[mi][ks2], bfr[nj][ks2], acc[mi][nj], 0, 0, 0);
  }

  #pragma unroll
  for (int nj = 0; nj < 4; ++nj) {
    int n = n0 + wn + nj * 16 + l15;
    float bv = bias[n];
    #pragma unroll
    for (int mi = 0; mi < 4; ++mi) {
      #pragma unroll
      for (int r = 0; r < 4; ++r) {
        int m = m0 + wm + mi * 16 + l4 * 4 + r;
        out[m * DIMM + n] = acc[mi][nj][r] + bv;
      }
    }
  }
}

extern "C" void kernel_launch(void* const* d_in, const int* in_sizes, int n_in,
                              void* d_out, int out_size, void* d_ws, size_t ws_size,
                              hipStream_t stream) {
  const float* x      = (const float*)d_in[0];
  const float* qkv_w  = (const float*)d_in[1];
  const float* qkv_b  = (const float*)d_in[2];
  const float* proj_w = (const float*)d_in[3];
  const float* proj_b = (const float*)d_in[4];
  const float* rph    = (const float*)d_in[5];
  const float* rpw    = (const float*)d_in[6];
  float* out = (float*)d_out;
  char* ws = (char*)d_ws;

  // workspace layout (ao aliases xb)
  u16*   xb     = (u16*)(ws + 0);          // 8192*768 bf16 (12.58 MB)
  u16*   wqkvb  = (u16*)(ws + 12582912);   // 2304*768
  u16*   wprojb = (u16*)(ws + 16121856);   // 768*768
  u16*   qb     = (u16*)(ws + 17301504);   // 96*1024*64
  u16*   kb     = (u16*)(ws + 29884416);
  u16*   vtb    = (u16*)(ws + 42467328);   // transposed V [bh][d][l]
  u16*   rphb   = (u16*)(ws + 55050240);   // padded bf16 [64][64]
  u16*   rpwb   = (u16*)(ws + 55058432);
  u16*   ao     = xb;                      // reuse after QKV GEMM consumed xb

  cvt_kernel<<<6144, 256, 0, stream>>>(x, xb, 8192 * 768 / 4);
  cvt_kernel<<<1728, 256, 0, stream>>>(qkv_w, wqkvb, 2304 * 768 / 4);
  cvt_kernel<<<576, 256, 0, stream>>>(proj_w, wprojb, 768 * 768 / 4);
  cvt_rel<<<32, 256, 0, stream>>>(rph, rpw, rphb, rpwb);

  gemm_qkv<<<64 * 18, 256, 0, stream>>>(xb, wqkvb, qkv_b, qb, kb, vtb);

  attn_kernel<<<96 * 16, 256, 0, stream>>>(qb, kb, vtb, rphb, rpwb, ao);

  gemm_proj<<<64 * 6, 256, 0, stream>>>(ao, wprojb, proj_b, out);
}

// Round 10
// 148.664 us; speedup vs baseline: 2.0546x; 2.0546x over previous
//
#include <hip/hip_runtime.h>

typedef unsigned short u16;
typedef __bf16 bf16x8 __attribute__((ext_vector_type(8)));
typedef float f32x4 __attribute__((ext_vector_type(4)));

#define NHEAD 12
#define LQ 1024
#define HDIM 64
#define DIMM 768

__device__ __forceinline__ u16 f2b(float f) {
  unsigned u = __float_as_uint(f);
  u += 0x7fffu + ((u >> 16) & 1u);   // RNE; inputs are finite
  return (u16)(u >> 16);
}
__device__ __forceinline__ float b2f(u16 v) {
  return __uint_as_float(((unsigned)v) << 16);
}
__device__ __forceinline__ unsigned cvt_pk(float lo, float hi) {
  unsigned r;
  asm("v_cvt_pk_bf16_f32 %0, %1, %2" : "=v"(r) : "v"(lo), "v"(hi));
  return r;
}
__device__ __forceinline__ void async16(const void* g, void* l) {
  __builtin_amdgcn_global_load_lds(
      (const __attribute__((address_space(1))) void*)g,
      (__attribute__((address_space(3))) void*)l, 16, 0, 0);
}
__device__ __forceinline__ uint2 shfl_u2(uint2 v, int src) {
  uint2 r;
  r.x = (unsigned)__shfl((int)v.x, src, 64);
  r.y = (unsigned)__shfl((int)v.y, src, 64);
  return r;
}

// ---------------- f32 -> bf16 convert ----------------
__global__ __launch_bounds__(256) void cvt_kernel(const float* __restrict__ in,
                                                  u16* __restrict__ out, int n4) {
  int i = blockIdx.x * 256 + threadIdx.x;
  if (i >= n4) return;
  const float4 v = reinterpret_cast<const float4*>(in)[i];
  ushort4 o;
  o.x = f2b(v.x); o.y = f2b(v.y); o.z = f2b(v.z); o.w = f2b(v.w);
  reinterpret_cast<ushort4*>(out)[i] = o;
}

// rel tables -> padded bf16 [64][64] (row 63 zero, never indexed)
__global__ __launch_bounds__(256) void cvt_rel(const float* __restrict__ rph,
                                               const float* __restrict__ rpw,
                                               u16* __restrict__ rphb,
                                               u16* __restrict__ rpwb) {
  int i = blockIdx.x * 256 + threadIdx.x;   // 0..8191
  int tab = i >> 12, idx = i & 4095;
  int m = idx >> 6, d = idx & 63;
  const float* src = tab ? rpw : rph;
  u16* dst = tab ? rpwb : rphb;
  dst[idx] = (m < 63) ? f2b(src[m * HDIM + d]) : (u16)0;
}

// ---------------- QKV GEMM: C = A(8192x768) * Bt(2304x768)^T + bias ----------------
// BK=64, dbuf, XCD swizzle, ^(row&7) involution staging (r8 structure).
// V-part epilogue: transpose through LDS (reuse la) -> coalesced 16B vtb stores
// (replaces the 2B x 64-distinct-lines scatter that inflated WRITE_SIZE 58MB).
__global__ __launch_bounds__(256) void gemm_qkv(const u16* __restrict__ A,
                                                const u16* __restrict__ Bt,
                                                const float* __restrict__ bias,
                                                u16* __restrict__ qb,
                                                u16* __restrict__ kb,
                                                u16* __restrict__ vtb) {
  __shared__ u16 la[2][128 * 64];
  __shared__ u16 lb[2][128 * 64];
  const int K = DIMM;
  int t = threadIdx.x;
  int lane = t & 63, wv = t >> 6;
  int l15 = lane & 15, l4 = lane >> 4;
  int swz = (blockIdx.x & 7) * 144 + (blockIdx.x >> 3);   // 1152 = 8*144
  int bm = swz / 18, bn = swz % 18;
  int m0 = bm * 128, n0 = bn * 128;
  int wm = (wv >> 1) * 64, wn = (wv & 1) * 64;

  auto stage = [&](int s, int buf) {
    int k0 = s * 64;
    #pragma unroll
    for (int i = 0; i < 4; ++i) {
      int c = i * 256 + t;
      int row = c >> 3, co = c & 7;
      int g = co ^ (row & 7);          // source pre-swizzle; LDS stays linear
      async16(A + (m0 + row) * K + k0 + g * 8, (char*)&la[buf][0] + c * 16);
      async16(Bt + (n0 + row) * K + k0 + g * 8, (char*)&lb[buf][0] + c * 16);
    }
  };

  f32x4 acc[4][4];
  #pragma unroll
  for (int i = 0; i < 4; ++i)
    #pragma unroll
    for (int j = 0; j < 4; ++j) acc[i][j] = {0.f, 0.f, 0.f, 0.f};

  stage(0, 0);
  #pragma unroll 2
  for (int s = 0; s < 12; ++s) {
    int cur = s & 1;
    __syncthreads();                      // drains own vmcnt(0): buf[cur] landed
    if (s + 1 < 12) stage(s + 1, cur ^ 1);
    bf16x8 af[4][2], bfr[4][2];
    #pragma unroll
    for (int mi = 0; mi < 4; ++mi) {
      int row = wm + mi * 16 + l15;
      #pragma unroll
      for (int ks2 = 0; ks2 < 2; ++ks2)
        af[mi][ks2] = *reinterpret_cast<const bf16x8*>(
            &la[cur][row * 64 + (((ks2 << 2) + l4) ^ (row & 7)) * 8]);
    }
    #pragma unroll
    for (int nj = 0; nj < 4; ++nj) {
      int row = wn + nj * 16 + l15;
      #pragma unroll
      for (int ks2 = 0; ks2 < 2; ++ks2)
        bfr[nj][ks2] = *reinterpret_cast<const bf16x8*>(
            &lb[cur][row * 64 + (((ks2 << 2) + l4) ^ (row & 7)) * 8]);
    }
    #pragma unroll
    for (int mi = 0; mi < 4; ++mi)
      #pragma unroll
      for (int nj = 0; nj < 4; ++nj)
        #pragma unroll
        for (int ks2 = 0; ks2 < 2; ++ks2)
          acc[mi][nj] = __builtin_amdgcn_mfma_f32_16x16x32_bf16(
              af[mi][ks2], bfr[nj][ks2], acc[mi][nj], 0, 0, 0);
  }

  int part = (n0 >> 7) / 6;  // 0:q 1:k 2:v (768 = 6 tiles of 128); block-uniform
  if (part < 2) {
    #pragma unroll
    for (int nj = 0; nj < 4; ++nj) {
      int n = n0 + wn + nj * 16 + l15;
      float bv = bias[n];
      int d = n & 63;
      int head = (n >> 6) % NHEAD;
      #pragma unroll
      for (int mi = 0; mi < 4; ++mi) {
        #pragma unroll
        for (int r = 0; r < 4; ++r) {
          int m = m0 + wm + mi * 16 + l4 * 4 + r;
          int b = m >> 10, li = m & 1023;
          int bh = b * NHEAD + head;
          u16 o = f2b(acc[mi][nj][r] + bv);
          if (part == 0) qb[(bh * LQ + li) * HDIM + d] = o;
          else           kb[(bh * LQ + li) * HDIM + d] = o;
        }
      }
    }
  } else {
    // V: transpose via LDS tile [n_local][m_local] (reuse la, 32KB exact).
    // 8B slots XOR-swizzled: col4s = col4 ^ ((row&7)<<2) — write 2-way (free),
    // read at the b128 structural floor.
    __syncthreads();                     // all waves done reading la
    u16* tile = &la[0][0];
    #pragma unroll
    for (int nj = 0; nj < 4; ++nj) {
      int rowl = wn + nj * 16 + l15;     // n_local
      float bv = bias[n0 + rowl];
      #pragma unroll
      for (int mi = 0; mi < 4; ++mi) {
        int col4 = (wm + mi * 16 + l4 * 4) >> 2;
        int col4s = col4 ^ ((rowl & 7) << 2);
        ushort4 o;
        o.x = f2b(acc[mi][nj][0] + bv);
        o.y = f2b(acc[mi][nj][1] + bv);
        o.z = f2b(acc[mi][nj][2] + bv);
        o.w = f2b(acc[mi][nj][3] + bv);
        *reinterpret_cast<ushort4*>(&tile[rowl * 128 + col4s * 4]) = o;
      }
    }
    __syncthreads();
    int b = m0 >> 10;
    int vn0 = n0 - 1536;
    #pragma unroll
    for (int i = 0; i < 8; ++i) {
      int c = i * 256 + t;
      int rowl = c >> 4, col16 = c & 15;
      int col4s = (col16 * 2) ^ ((rowl & 7) << 2);
      uint4 v = *reinterpret_cast<const uint4*>(&tile[rowl * 128 + col4s * 4]);
      int vn = vn0 + rowl;
      int bh = b * NHEAD + (vn >> 6);
      int d = vn & 63;
      int li0 = (m0 & 1023) + col16 * 8;
      *reinterpret_cast<uint4*>(&vtb[(bh * HDIM + d) * LQ + li0]) = v;
    }
  }
}

// ---------------- flash attention with fused decomposed rel-pos bias ----------------
// (r8 version, verbatim: LDS-staged K/V dbuf + XCD swizzle; swapped mfma(K,Q)/
// mfma(V,P); in-register P redistribution; Tw hoisted to registers)
__global__ __launch_bounds__(256) void attn_kernel(const u16* __restrict__ qb,
                                                   const u16* __restrict__ kb,
                                                   const u16* __restrict__ vtb,
                                                   const u16* __restrict__ rphb,
                                                   const u16* __restrict__ rpwb,
                                                   u16* __restrict__ ao) {
  __shared__ u16 lds_k[2][64 * 64];    // [key][d], source-swizzled
  __shared__ u16 lds_v[2][64 * 64];    // [d][key], source-swizzled
  __shared__ u16 lds_th[64 * 72];      // T-tables, bf16, padded stride 72
  __shared__ u16 lds_tw[64 * 72];
  // total 51200 B -> 3 blocks/CU

  int swz = (blockIdx.x & 7) * 192 + (blockIdx.x >> 3);   // 1536 = 8*192
  int bh = swz >> 4;
  int q0 = (swz & 15) * 64;
  int t = threadIdx.x;
  int wv = t >> 6, lane = t & 63;
  int l15 = lane & 15, l4 = lane >> 4;

  auto stagekv = [&](int kv0, int buf) {
    const u16* ks = kb + (bh * LQ + kv0) * HDIM;
    const u16* vs = vtb + bh * HDIM * LQ + kv0;
    #pragma unroll
    for (int i = 0; i < 2; ++i) {
      int c = i * 256 + t;
      int row = c >> 3, co = c & 7;
      int g = co ^ (row & 7);          // source swizzle; LDS stays linear
      async16(ks + row * HDIM + g * 8, (char*)&lds_k[buf][0] + c * 16);
      async16(vs + row * LQ + g * 8, (char*)&lds_v[buf][0] + c * 16);
    }
  };

  stagekv(0, 0);                       // chunk 0 flies under the T-table prologue

  // Q fragments (2 x K=32) straight from global
  bf16x8 qf[2];
  {
    const u16* qsrc = qb + (bh * LQ + q0 + wv * 16 + l15) * HDIM + l4 * 8;
    qf[0] = *reinterpret_cast<const bf16x8*>(qsrc);
    qf[1] = *reinterpret_cast<const bf16x8*>(qsrc + 32);
  }

  // T-tables via MFMA: wave wv owns rows [wv*16, wv*16+16) (wave-private)
  #pragma unroll
  for (int c = 0; c < 4; ++c) {
    f32x4 th = {0.f, 0.f, 0.f, 0.f}, tw = {0.f, 0.f, 0.f, 0.f};
    #pragma unroll
    for (int ks2 = 0; ks2 < 2; ++ks2) {
      bf16x8 bhf = *reinterpret_cast<const bf16x8*>(&rphb[(c * 16 + l15) * HDIM + ks2 * 32 + l4 * 8]);
      bf16x8 bwf = *reinterpret_cast<const bf16x8*>(&rpwb[(c * 16 + l15) * HDIM + ks2 * 32 + l4 * 8]);
      th = __builtin_amdgcn_mfma_f32_16x16x32_bf16(qf[ks2], bhf, th, 0, 0, 0);
      tw = __builtin_amdgcn_mfma_f32_16x16x32_bf16(qf[ks2], bwf, tw, 0, 0, 0);
    }
    #pragma unroll
    for (int r = 0; r < 4; ++r) {
      int row = wv * 16 + l4 * 4 + r;
      lds_th[row * 72 + c * 16 + l15] = f2b(th[r]);
      lds_tw[row * 72 + c * 16 + l15] = f2b(tw[r]);
    }
  }

  // per-lane row constants (lane owns q-row l15 of its wave's 16 rows)
  int gq = q0 + wv * 16 + l15;
  int hq = gq >> 5, wq = gq & 31;
  int lrow = wv * 16 + l15;
  const u16* thp = &lds_th[lrow * 72 + hq + 31];   // [-k1]
  const u16* twp = &lds_tw[lrow * 72 + wq + 31];   // [-k2]

  // Tw hoist: only 8 distinct Tw values per lane, chunk-invariant. Load once.
  float tw_reg[8];
  #pragma unroll
  for (int j = 0; j < 8; ++j) {
    int k2 = (j >> 2) * 16 + l4 * 4 + (j & 3);
    tw_reg[j] = b2f(twp[-k2]);
  }

  float m_run = -1e30f, l_run = 0.f;
  f32x4 acc_o[4];
  #pragma unroll
  for (int dj = 0; dj < 4; ++dj) acc_o[dj] = {0.f, 0.f, 0.f, 0.f};

  // bpermute sources for P redistribution (fixed per lane)
  int srcA = l15 + (l4 & 1) * 32;
  int srcB = srcA + 16;
  bool hiG = (l4 >> 1) & 1;

  #pragma unroll 2
  for (int cidx = 0; cidx < 16; ++cidx) {
    int cur = cidx & 1;
    int kv0 = cidx * 64;
    __syncthreads();                   // drains own vmcnt(0): buf[cur] K/V landed
    if (cidx + 1 < 16) stagekv(kv0 + 64, cur ^ 1);

    // QK^T swapped: C[col=qrow=l15][row=key]; lane -> keys kv0 + nj*16 + l4*4 + r
    f32x4 sc[4];
    __builtin_amdgcn_s_setprio(1);
    #pragma unroll
    for (int nj = 0; nj < 4; ++nj) {
      f32x4 a = {0.f, 0.f, 0.f, 0.f};
      #pragma unroll
      for (int ks2 = 0; ks2 < 2; ++ks2) {
        int co = (ks2 * 4 + l4) ^ (l15 & 7);
        bf16x8 kf = *reinterpret_cast<const bf16x8*>(&lds_k[cur][(nj * 16 + l15) * 64 + co * 8]);
        a = __builtin_amdgcn_mfma_f32_16x16x32_bf16(kf, qf[ks2], a, 0, 0, 0);
      }
      sc[nj] = a;
    }
    __builtin_amdgcn_s_setprio(0);

    // scores + bias (all 16 belong to q-row l15)
    int kv5 = kv0 >> 5;
    float th0 = b2f(thp[-kv5]);        // k1 = kv5   (nj 0,1)
    float th1 = b2f(thp[-kv5 - 1]);    // k1 = kv5+1 (nj 2,3)
    float p[4][4];
    float cmax = -1e30f;
    #pragma unroll
    for (int nj = 0; nj < 4; ++nj) {
      float thv = (nj < 2) ? th0 : th1;
      #pragma unroll
      for (int r = 0; r < 4; ++r) {
        float s = fmaf(sc[nj][r], 0.125f, thv) + tw_reg[(nj & 1) * 4 + r];
        p[nj][r] = s;
        cmax = fmaxf(cmax, s);
      }
    }
    cmax = fmaxf(cmax, __shfl_xor(cmax, 16));
    cmax = fmaxf(cmax, __shfl_xor(cmax, 32));

    // defer-max (T13): rescale only when some row grew by > 8
    if (!__all(cmax <= m_run + 8.0f)) {
      float mn = fmaxf(m_run, cmax);
      float scl = __expf(m_run - mn);
      m_run = mn;
      l_run *= scl;
      #pragma unroll
      for (int dj = 0; dj < 4; ++dj)
        #pragma unroll
        for (int r = 0; r < 4; ++r) acc_o[dj][r] *= scl;
    }

    float psum = 0.f;
    #pragma unroll
    for (int nj = 0; nj < 4; ++nj)
      #pragma unroll
      for (int r = 0; r < 4; ++r) {
        p[nj][r] = __expf(p[nj][r] - m_run);
        psum += p[nj][r];
      }
    psum += __shfl_xor(psum, 16);
    psum += __shfl_xor(psum, 32);
    l_run += psum;

    // P -> bf16 packed, redistribute to B-fragment layout in-register (T12):
    // pf[ks2][i] = P[l15][ks2*32 + l4*8 + i]
    uint2 w4[4];
    #pragma unroll
    for (int nj = 0; nj < 4; ++nj) {
      w4[nj].x = cvt_pk(p[nj][0], p[nj][1]);
      w4[nj].y = cvt_pk(p[nj][2], p[nj][3]);
    }
    bf16x8 pf[2];
    #pragma unroll
    for (int ks2 = 0; ks2 < 2; ++ks2) {
      uint2 lo0 = shfl_u2(w4[ks2 * 2 + 0], srcA);
      uint2 lo1 = shfl_u2(w4[ks2 * 2 + 1], srcA);
      uint2 hi0 = shfl_u2(w4[ks2 * 2 + 0], srcB);
      uint2 hi1 = shfl_u2(w4[ks2 * 2 + 1], srcB);
      union { uint4 u; bf16x8 b; } cv;
      cv.u.x = hiG ? lo1.x : lo0.x;
      cv.u.y = hiG ? lo1.y : lo0.y;
      cv.u.z = hiG ? hi1.x : hi0.x;
      cv.u.w = hiG ? hi1.y : hi0.y;
      pf[ks2] = cv.b;
    }

    // PV swapped: acc_o[dj] holds O^T[d = dj*16+4*l4+r][qrow = l15]
    __builtin_amdgcn_s_setprio(1);
    #pragma unroll
    for (int dj = 0; dj < 4; ++dj) {
      int d = dj * 16 + l15;
      #pragma unroll
      for (int ks2 = 0; ks2 < 2; ++ks2) {
        int co = (ks2 * 4 + l4) ^ (l15 & 7);
        bf16x8 vf = *reinterpret_cast<const bf16x8*>(&lds_v[cur][d * 64 + co * 8]);
        acc_o[dj] = __builtin_amdgcn_mfma_f32_16x16x32_bf16(vf, pf[ks2], acc_o[dj], 0, 0, 0);
      }
    }
    __builtin_amdgcn_s_setprio(0);
  }

  // epilogue: normalize, packed 8B stores; lane owns q-row gq, d = dj*16 + l4*4 + r
  int b = bh / NHEAD, head = bh % NHEAD;
  float inv = 1.f / l_run;
  u16* orow = ao + (b * LQ + gq) * DIMM + head * HDIM;
  #pragma unroll
  for (int dj = 0; dj < 4; ++dj) {
    uint2 pk;
    pk.x = cvt_pk(acc_o[dj][0] * inv, acc_o[dj][1] * inv);
    pk.y = cvt_pk(acc_o[dj][2] * inv, acc_o[dj][3] * inv);
    *reinterpret_cast<uint2*>(&orow[dj * 16 + l4 * 4]) = pk;
  }
}

// ---------------- proj GEMM: out = A(8192x768) * Bt(768x768)^T + bias (f32 out) ----------------
__global__ __launch_bounds__(256) void gemm_proj(const u16* __restrict__ A,
                                                 const u16* __restrict__ Bt,
                                                 const float* __restrict__ bias,
                                                 float* __restrict__ out) {
  __shared__ u16 la[2][128 * 64];
  __shared__ u16 lb[2][128 * 64];
  const int K = DIMM;
  int t = threadIdx.x;
  int lane = t & 63, wv = t >> 6;
  int l15 = lane & 15, l4 = lane >> 4;
  int swz = (blockIdx.x & 7) * 48 + (blockIdx.x >> 3);    // 384 = 8*48
  int bm = swz / 6, bn = swz % 6;
  int m0 = bm * 128, n0 = bn * 128;
  int wm = (wv >> 1) * 64, wn = (wv & 1) * 64;

  auto stage = [&](int s, int buf) {
    int k0 = s * 64;
    #pragma unroll
    for (int i = 0; i < 4; ++i) {
      int c = i * 256 + t;
      int row = c >> 3, co = c & 7;
      int g = co ^ (row & 7);
      async16(A + (m0 + row) * K + k0 + g * 8, (char*)&la[buf][0] + c * 16);
      async16(Bt + (n0 + row) * K + k0 + g * 8, (char*)&lb[buf][0] + c * 16);
    }
  };

  f32x4 acc[4][4];
  #pragma unroll
  for (int i = 0; i < 4; ++i)
    #pragma unroll
    for (int j = 0; j < 4; ++j) acc[i][j] = {0.f, 0.f, 0.f, 0.f};

  stage(0, 0);
  #pragma unroll 2
  for (int s = 0; s < 12; ++s) {
    int cur = s & 1;
    __syncthreads();
    if (s + 1 < 12) stage(s + 1, cur ^ 1);
    bf16x8 af[4][2], bfr[4][2];
    #pragma unroll
    for (int mi = 0; mi < 4; ++mi) {
      int row = wm + mi * 16 + l15;
      #pragma unroll
      for (int ks2 = 0; ks2 < 2; ++ks2)
        af[mi][ks2] = *reinterpret_cast<const bf16x8*>(
            &la[cur][row * 64 + (((ks2 << 2) + l4) ^ (row & 7)) * 8]);
    }
    #pragma unroll
    for (int nj = 0; nj < 4; ++nj) {
      int row = wn + nj * 16 + l15;
      #pragma unroll
      for (int ks2 = 0; ks2 < 2; ++ks2)
        bfr[nj][ks2] = *reinterpret_cast<const bf16x8*>(
            &lb[cur][row * 64 + (((ks2 << 2) + l4) ^ (row & 7)) * 8]);
    }
    #pragma unroll
    for (int mi = 0; mi < 4; ++mi)
      #pragma unroll
      for (int nj = 0; nj < 4; ++nj)
        #pragma unroll
        for (int ks2 = 0; ks2 < 2; ++ks2)
          acc[mi][nj] = __builtin_amdgcn_mfma_f32_16x16x32_bf16(
              af[mi][ks2], bfr[nj][ks2], acc[mi][nj], 0, 0, 0);
  }

  #pragma unroll
  for (int nj = 0; nj < 4; ++nj) {
    int n = n0 + wn + nj * 16 + l15;
    float bv = bias[n];
    #pragma unroll
    for (int mi = 0; mi < 4; ++mi) {
      #pragma unroll
      for (int r = 0; r < 4; ++r) {
        int m = m0 + wm + mi * 16 + l4 * 4 + r;
        out[m * DIMM + n] = acc[mi][nj][r] + bv;
      }
    }
  }
}

extern "C" void kernel_launch(void* const* d_in, const int* in_sizes, int n_in,
                              void* d_out, int out_size, void* d_ws, size_t ws_size,
                              hipStream_t stream) {
  const float* x      = (const float*)d_in[0];
  const float* qkv_w  = (const float*)d_in[1];
  const float* qkv_b  = (const float*)d_in[2];
  const float* proj_w = (const float*)d_in[3];
  const float* proj_b = (const float*)d_in[4];
  const float* rph    = (const float*)d_in[5];
  const float* rpw    = (const float*)d_in[6];
  float* out = (float*)d_out;
  char* ws = (char*)d_ws;

  // workspace layout (ao aliases xb)
  u16*   xb     = (u16*)(ws + 0);          // 8192*768 bf16 (12.58 MB)
  u16*   wqkvb  = (u16*)(ws + 12582912);   // 2304*768
  u16*   wprojb = (u16*)(ws + 16121856);   // 768*768
  u16*   qb     = (u16*)(ws + 17301504);   // 96*1024*64
  u16*   kb     = (u16*)(ws + 29884416);
  u16*   vtb    = (u16*)(ws + 42467328);   // transposed V [bh][d][l]
  u16*   rphb   = (u16*)(ws + 55050240);   // padded bf16 [64][64]
  u16*   rpwb   = (u16*)(ws + 55058432);
  u16*   ao     = xb;                      // reuse after QKV GEMM consumed xb

  cvt_kernel<<<6144, 256, 0, stream>>>(x, xb, 8192 * 768 / 4);
  cvt_kernel<<<1728, 256, 0, stream>>>(qkv_w, wqkvb, 2304 * 768 / 4);
  cvt_kernel<<<576, 256, 0, stream>>>(proj_w, wprojb, 768 * 768 / 4);
  cvt_rel<<<32, 256, 0, stream>>>(rph, rpw, rphb, rpwb);

  gemm_qkv<<<64 * 18, 256, 0, stream>>>(xb, wqkvb, qkv_b, qb, kb, vtb);

  attn_kernel<<<96 * 16, 256, 0, stream>>>(qb, kb, vtb, rphb, rpwb, ao);

  gemm_proj<<<64 * 6, 256, 0, stream>>>(ao, wprojb, proj_b, out);
}